// Round 17
// baseline (65.318 us; speedup 1.0000x reference)
//
#include <hip/hip_runtime.h>

#define NJ 22
#define CAM_DIM 3

// Gram-Schmidt 6D->3x3 (ROMP convention). r[] holds b1,b2,b3 as rows of storage;
// both sides of every dot use the same layout, so orientation is consistent.
__device__ __forceinline__ void rot6(const float* __restrict__ p, float r[9]) {
    float a1x = p[0], a2x = p[1];
    float a1y = p[2], a2y = p[3];
    float a1z = p[4], a2z = p[5];
    float n1 = sqrtf(a1x*a1x + a1y*a1y + a1z*a1z);
    float b1x = a1x/n1, b1y = a1y/n1, b1z = a1z/n1;
    float d = b1x*a2x + b1y*a2y + b1z*a2z;
    float px = a2x - d*b1x, py = a2y - d*b1y, pz = a2z - d*b1z;
    float np = sqrtf(px*px + py*py + pz*pz);
    float b2x = px/np, b2y = py/np, b2z = pz/np;
    r[0]=b1x; r[1]=b1y; r[2]=b1z;
    r[3]=b2x; r[4]=b2y; r[5]=b2z;
    r[6]=b1y*b2z - b1z*b2y;
    r[7]=b1z*b2x - b1x*b2z;
    r[8]=b1x*b2y - b1y*b2x;
}

// MEASUREMENT BUILD: the round-8 kernel body executed `reps` times in one
// dispatch (idempotent: every pass computes and stores identical values).
// Purpose: (a) make the dispatch long enough to surface in the top-5 rocprof
// table with full counters; (b) discriminate in-wave latency (per-rep stays
// ~10.6us) vs dispatch/ramp (per-rep collapses once blocks are long-lived).
__global__ __launch_bounds__(256) void mega_kernel(
        const float* __restrict__ params,
        const int* __restrict__ batch_ids,
        const int* __restrict__ czyx,
        const float* __restrict__ ts,
        float* __restrict__ out,
        float* __restrict__ nms,
        int n, int param_dim, int reps) {
    __shared__ unsigned long long s_red[4];

    const int i    = blockIdx.x;
    const int tid  = threadIdx.x;
    const int lane = tid & 63;
    const int wid  = tid >> 6;

    const int bi  = batch_ids[i];
    const int ciy = czyx[3*i + 1];
    const int cix = czyx[3*i + 2];
    float* row = out + (size_t)i * n;

    for (int rep = 0; rep < reps; ++rep) {
        __syncthreads();   // protects s_red reuse across reps
        // defeat cross-rep CSE of the whole body
        asm volatile("" ::: "memory");

        unsigned long long best = 0ull;

        for (int base = 0; base < n; base += blockDim.x * 4) {
            int j0 = base + tid * 4;
            if (j0 >= n) continue;

            int okmask = 0;
            if (j0 + 3 < n) {
                int4 b4 = *reinterpret_cast<const int4*>(batch_ids + j0);
                const int4* cz = reinterpret_cast<const int4*>(czyx + 3*j0);
                int4 c0 = cz[0], c1 = cz[1], c2 = cz[2];
                int by[4] = {b4.x, b4.y, b4.z, b4.w};
                int yy[4] = {c0.y, c1.x, c1.w, c2.z};
                int xx[4] = {c0.z, c1.y, c2.x, c2.w};
                #pragma unroll
                for (int u = 0; u < 4; ++u) {
                    int dy = yy[u] - ciy, dx = xx[u] - cix;
                    if ((by[u] == bi) && (dy*dy + dx*dx <= 25)) okmask |= 1 << u;
                }
            } else {
                for (int u = 0; u < 4 && j0 + u < n; ++u) {
                    int j = j0 + u;
                    int dy = czyx[3*j + 1] - ciy, dx = czyx[3*j + 2] - cix;
                    if ((batch_ids[j] == bi) && (dy*dy + dx*dx <= 25)) okmask |= 1 << u;
                }
            }

            int passmask = 0;
            int du = i - j0;
            if (du >= 0 && du < 4) {
                passmask |=  (1 << du);
                okmask   &= ~(1 << du);
            }

            // wave-cooperative pose evaluation of the rare gate hits
            for (;;) {
                unsigned long long pend = __ballot(okmask != 0);
                if (pend == 0ull) break;
                int leader = __ffsll((long long)pend) - 1;
                int lok = __shfl(okmask, leader);
                int u   = __ffs(lok) - 1;
                int j   = __shfl(j0, leader) + u;

                float val = 0.0f;
                if (lane < NJ) {
                    const float* pi_ = params + (size_t)i * param_dim + CAM_DIM + lane * 6;
                    const float* pj_ = params + (size_t)j * param_dim + CAM_DIM + lane * 6;
                    float ri[9], rj[9];
                    rot6(pi_, ri);
                    rot6(pj_, rj);
                    float g = 0.0f, ni = 0.0f, nj = 0.0f;
                    #pragma unroll
                    for (int a = 0; a < 9; ++a) {
                        g  += ri[a]*rj[a];
                        ni += ri[a]*ri[a];
                        nj += rj[a]*rj[a];
                    }
                    val = sqrtf(fmaxf(ni + nj - 2.0f*g, 0.0f));
                }
                #pragma unroll
                for (int off = 16; off > 0; off >>= 1) val += __shfl_down(val, off, 32);
                float pd = __shfl(val, 0) * (1.0f / 22.0f);

                if (lane == leader) {
                    okmask &= ~(1 << u);
                    if (pd < 2.5f) passmask |= 1 << u;
                }
            }

            float sc[4];
            #pragma unroll
            for (int u = 0; u < 4; ++u)
                sc[u] = ((passmask >> u) & 1) ? ts[j0 + u] : 0.0f;

            unsigned long long cand = (unsigned int)(~(unsigned int)j0);
            if (cand > best) best = cand;
            #pragma unroll
            for (int u = 0; u < 4; ++u) {
                if ((passmask >> u) & 1) {
                    unsigned long long p =
                        ((unsigned long long)__float_as_uint(sc[u]) << 32) |
                        (unsigned int)(~(unsigned int)(j0 + u));
                    if (p > best) best = p;
                }
            }

            if (j0 + 3 < n) {
                *reinterpret_cast<float4*>(row + j0) = make_float4(sc[0], sc[1], sc[2], sc[3]);
            } else {
                for (int u = 0; u < 4 && j0 + u < n; ++u) row[j0 + u] = sc[u];
            }
        }

        #pragma unroll
        for (int off = 32; off > 0; off >>= 1) {
            unsigned long long o = __shfl_xor(best, off);
            if (o > best) best = o;
        }
        if (lane == 0) s_red[wid] = best;
        __syncthreads();
        if (tid == 0) {
            unsigned long long b = s_red[0];
            #pragma unroll
            for (int w = 1; w < 4; ++w) if (s_red[w] > b) b = s_red[w];
            unsigned int jwin = ~(unsigned int)(b & 0xFFFFFFFFull);
            nms[i] = (jwin == (unsigned int)i) ? 1.0f : 0.0f;
        }
    }
}

extern "C" void kernel_launch(void* const* d_in, const int* in_sizes, int n_in,
                              void* d_out, int out_size, void* d_ws, size_t ws_size,
                              hipStream_t stream) {
    const float* params = (const float*)d_in[0];
    const int*   batch  = (const int*)d_in[1];
    const int*   czyx   = (const int*)d_in[2];
    const float* ts     = (const float*)d_in[3];

    const int n = in_sizes[1];                 // N = 2048
    const int param_dim = in_sizes[0] / n;     // 145

    float* out = (float*)d_out;        // score_map [n*n]
    float* nms = out + (size_t)n * n;  // nms_inds [n] as 0/1 floats

    // 8 idempotent full passes in ONE dispatch (measurement round; see header).
    mega_kernel<<<n, 256, 0, stream>>>(params, batch, czyx, ts, out, nms,
                                       n, param_dim, 8);
}

// Round 18
// 15.325 us; speedup vs baseline: 4.2623x; 4.2623x over previous
//
#include <hip/hip_runtime.h>

#define NJ 22
#define CAM_DIM 3
#define HITCAP 128

// Gram-Schmidt 6D->3x3 (ROMP convention). r[] holds b1,b2,b3 as rows of storage;
// both sides of every dot use the same layout, so orientation is consistent.
__device__ __forceinline__ void rot6(const float* __restrict__ p, float r[9]) {
    float a1x = p[0], a2x = p[1];
    float a1y = p[2], a2y = p[3];
    float a1z = p[4], a2z = p[5];
    float n1 = sqrtf(a1x*a1x + a1y*a1y + a1z*a1z);
    float b1x = a1x/n1, b1y = a1y/n1, b1z = a1z/n1;
    float d = b1x*a2x + b1y*a2y + b1z*a2z;
    float px = a2x - d*b1x, py = a2y - d*b1y, pz = a2z - d*b1z;
    float np = sqrtf(px*px + py*py + pz*pz);
    float b2x = px/np, b2y = py/np, b2z = pz/np;
    r[0]=b1x; r[1]=b1y; r[2]=b1z;
    r[3]=b2x; r[4]=b2y; r[5]=b2z;
    r[6]=b1y*b2z - b1z*b2y;
    r[7]=b1z*b2x - b1x*b2z;
    r[8]=b1x*b2y - b1y*b2x;
}

// One block per row. Phase 1 (hot): branchless optimistic stream — gate 8 j's,
// store ts[j] where gated else 0, push rare off-diag hits to an LDS list.
// Phase 2 (rare): 4 waves split the hit list, wave-coop pose, overwrite
// failures with 0, fold argmax (diag + passes + zero floor) -> nms[i].
__global__ __launch_bounds__(256) void fused_kernel(
        const float* __restrict__ params,
        const int* __restrict__ batch_ids,
        const int* __restrict__ czyx,
        const float* __restrict__ ts,
        float* __restrict__ out,
        float* __restrict__ nms,
        int n, int param_dim) {
    __shared__ int l_cnt;
    __shared__ int l_hits[HITCAP];
    __shared__ unsigned long long l_best[4];

    const int i    = blockIdx.x;
    const int tid  = threadIdx.x;
    const int lane = tid & 63;
    const int wid  = tid >> 6;

    if (tid == 0) l_cnt = 0;
    __syncthreads();

    const int bi  = batch_ids[i];
    const int ciy = czyx[3*i + 1];
    const int cix = czyx[3*i + 2];
    float* row = out + (size_t)i * n;

    // ---------- Phase 1: branchless optimistic stream ----------
    for (int j0 = tid * 8; j0 < n; j0 += blockDim.x * 8) {
        int okmask = 0;
        float tsv[8];
        if (j0 + 7 < n) {
            int4 ba = *reinterpret_cast<const int4*>(batch_ids + j0);
            int4 bb = *reinterpret_cast<const int4*>(batch_ids + j0 + 4);
            const int4* cz = reinterpret_cast<const int4*>(czyx + 3*j0);
            int4 c0 = cz[0], c1 = cz[1], c2 = cz[2], c3 = cz[3], c4 = cz[4], c5 = cz[5];
            float4 t0 = *reinterpret_cast<const float4*>(ts + j0);
            float4 t1 = *reinterpret_cast<const float4*>(ts + j0 + 4);
            int by[8] = {ba.x, ba.y, ba.z, ba.w, bb.x, bb.y, bb.z, bb.w};
            int yy[8] = {c0.y, c1.x, c1.w, c2.z, c3.y, c4.x, c4.w, c5.z};
            int xx[8] = {c0.z, c1.y, c2.x, c2.w, c3.z, c4.y, c5.x, c5.w};
            tsv[0]=t0.x; tsv[1]=t0.y; tsv[2]=t0.z; tsv[3]=t0.w;
            tsv[4]=t1.x; tsv[5]=t1.y; tsv[6]=t1.z; tsv[7]=t1.w;
            #pragma unroll
            for (int u = 0; u < 8; ++u) {
                int dy = yy[u] - ciy, dx = xx[u] - cix;
                if ((by[u] == bi) && (dy*dy + dx*dx <= 25)) okmask |= 1 << u;
            }
        } else {
            #pragma unroll
            for (int u = 0; u < 8; ++u) {
                int j = j0 + u;
                bool v = j < n;
                int dy = v ? czyx[3*j + 1] - ciy : 1000;
                int dx = v ? czyx[3*j + 2] - cix : 1000;
                tsv[u] = v ? ts[j] : 0.0f;
                if (v && (batch_ids[j] == bi) && (dy*dy + dx*dx <= 25)) okmask |= 1 << u;
            }
        }

        // diagonal passes exactly in the reference; exclude from pose-pending
        int pending = okmask;
        int du = i - j0;
        if (du >= 0 && du < 8) pending &= ~(1 << du);

        // optimistic scores (pose failures fixed up in phase 2)
        float sc[8];
        #pragma unroll
        for (int u = 0; u < 8; ++u)
            sc[u] = ((okmask >> u) & 1) ? tsv[u] : 0.0f;

        if (j0 + 7 < n) {
            *reinterpret_cast<float4*>(row + j0)     = make_float4(sc[0],sc[1],sc[2],sc[3]);
            *reinterpret_cast<float4*>(row + j0 + 4) = make_float4(sc[4],sc[5],sc[6],sc[7]);
        } else {
            for (int u = 0; u < 8 && j0 + u < n; ++u) row[j0 + u] = sc[u];
        }

        while (pending) {                     // rare (~1.3 appends per block)
            int u = __ffs(pending) - 1;
            pending &= pending - 1;
            int pos = atomicAdd(&l_cnt, 1);
            if (pos < HITCAP) l_hits[pos] = j0 + u;
        }
    }

    __syncthreads();

    // ---------- Phase 2: deferred pose fixup + argmax ----------
    const int cnt = l_cnt < HITCAP ? l_cnt : HITCAP;

    // seed: wave 0 carries the diagonal candidate and the zero floor
    unsigned long long mybest = 0ull;
    if (wid == 0 && lane == 0) {
        mybest = ((unsigned long long)__float_as_uint(ts[i]) << 32) |
                 (unsigned int)(~(unsigned int)i);
        unsigned long long zfloor = (unsigned int)0xFFFFFFFFu;   // (0.0f, j=0)
        if (zfloor > mybest) mybest = zfloor;
    }

    if (cnt > wid) {                          // wave-uniform: wave w owns hits w::4
        float ri[9];
        float n2i = 0.0f;
        if (lane < NJ) {
            rot6(params + (size_t)i * param_dim + CAM_DIM + lane * 6, ri);
            #pragma unroll
            for (int a = 0; a < 9; ++a) n2i += ri[a] * ri[a];
        }

        for (int h = wid; h < cnt; h += 4) {
            int j = l_hits[h];
            float val = 0.0f;
            if (lane < NJ) {
                float rj[9];
                rot6(params + (size_t)j * param_dim + CAM_DIM + lane * 6, rj);
                float g = 0.0f, nj = 0.0f;
                #pragma unroll
                for (int a = 0; a < 9; ++a) {
                    g  += ri[a] * rj[a];
                    nj += rj[a] * rj[a];
                }
                val = sqrtf(fmaxf(n2i + nj - 2.0f*g, 0.0f));
            }
            #pragma unroll
            for (int off = 16; off > 0; off >>= 1) val += __shfl_down(val, off, 32);
            float pd = __shfl(val, 0) * (1.0f / 22.0f);

            if (lane == 0) {
                if (pd < 2.5f) {
                    unsigned long long p =
                        ((unsigned long long)__float_as_uint(ts[j]) << 32) |
                        (unsigned int)(~(unsigned int)j);
                    if (p > mybest) mybest = p;
                } else {
                    row[j] = 0.0f;            // fix up the optimistic store
                }
            }
        }
    }

    if (lane == 0) l_best[wid] = mybest;
    __syncthreads();
    if (tid == 0) {
        unsigned long long b = l_best[0];
        #pragma unroll
        for (int w = 1; w < 4; ++w) if (l_best[w] > b) b = l_best[w];
        unsigned int jwin = ~(unsigned int)(b & 0xFFFFFFFFull);
        nms[i] = (jwin == (unsigned int)i) ? 1.0f : 0.0f;
    }
}

extern "C" void kernel_launch(void* const* d_in, const int* in_sizes, int n_in,
                              void* d_out, int out_size, void* d_ws, size_t ws_size,
                              hipStream_t stream) {
    const float* params = (const float*)d_in[0];
    const int*   batch  = (const int*)d_in[1];
    const int*   czyx   = (const int*)d_in[2];
    const float* ts     = (const float*)d_in[3];

    const int n = in_sizes[1];                 // N = 2048
    const int param_dim = in_sizes[0] / n;     // 145

    float* out = (float*)d_out;        // score_map [n*n]
    float* nms = out + (size_t)n * n;  // nms_inds [n] as 0/1 floats

    fused_kernel<<<n, 256, 0, stream>>>(params, batch, czyx, ts,
                                        out, nms, n, param_dim);
}